// Round 15
// baseline (372.301 us; speedup 1.0000x reference)
//
#include <hip/hip_runtime.h>

// GNN: 2-layer edge-coloured conv on MI355X.
// Round 15: (1) k_gemm2g 32x96 waves, acc[2][6], 4 waves/SIMD (occupancy was
// the 14%-MfmaUtil wall); (2) k_final flattened per-dst edge walk with
// colour-packed slots (sv = src*8+c), 4-deep prefetch.

#define NN 50000
#define EE 800000
#define DD 128
#define HH 256
#define CC 8
#define K1 1152   // C*D + D

typedef unsigned short u16;
typedef __attribute__((ext_vector_type(8))) short s16x8;
typedef __attribute__((ext_vector_type(4))) float f32x4;

__device__ __forceinline__ float bf2f(short u) {
  return __uint_as_float(((unsigned)(u16)u) << 16);
}
__device__ __forceinline__ u16 f2bf(float f) {
  unsigned u = __float_as_uint(f);
  u = (u + 0x7FFFu + ((u >> 16) & 1u)) >> 16;   // RNE
  return (u16)u;
}

// ---------------- prep ----------------

__global__ void k_castx(const float* __restrict__ x, u16* __restrict__ xb) {
  int i = blockIdx.x * 256 + threadIdx.x;
  if (i < NN * DD) xb[i] = f2bf(x[i]);
}

// W1f fragment-major: idx = (((col16*36 + kk)*4 + kg)*16 + rs)*8 + e
__global__ void k_wt1f(const float* __restrict__ Wc1, const float* __restrict__ Ws1,
                       u16* __restrict__ W) {
  int i = blockIdx.x * 256 + threadIdx.x;
  if (i >= 294912) return;
  int e = i & 7;
  int t = i >> 3;
  int rs = t & 15; t >>= 4;
  int kg = t & 3;  t >>= 2;
  int kk = t % 36;
  int col16 = t / 36;
  int col = col16 * 16 + rs;
  int k = kk * 32 + kg * 8 + e;
  float v = (k < CC * DD) ? Wc1[(k >> 7) * (HH * DD) + col * DD + (k & 127)]
                          : Ws1[col * DD + (k - CC * DD)];
  W[i] = f2bf(v);
}

// W2f fragment-major: idx = (((col16*8 + kk)*4 + kg)*16 + rs)*8 + e
__global__ void k_wt2f(const float* __restrict__ Wc2, const float* __restrict__ Ws2,
                       u16* __restrict__ W) {
  int i = blockIdx.x * 256 + threadIdx.x;
  if (i >= 294912) return;
  int e = i & 7;
  int t = i >> 3;
  int rs = t & 15; t >>= 4;
  int kg = t & 3;  t >>= 2;
  int kk = t & 7;
  int col16 = t >> 3;
  int oc = col16 * 16 + rs;
  int c = oc >> 7, o = oc & 127;
  int k = kk * 32 + kg * 8 + e;
  float v = (c < CC) ? Wc2[c * (DD * HH) + o * HH + k] : Ws2[o * HH + k];
  W[i] = f2bf(v);
}

// ---------------- CSR build over seg = dst*8 + c ----------------

__global__ void k_hist(const int* __restrict__ ei, const int* __restrict__ ec,
                       int* __restrict__ counts) {
  int e = blockIdx.x * 256 + threadIdx.x;
  if (e < EE) {
    int dst = ei[EE + e];
    int c = ec[e];
    atomicAdd(&counts[dst * CC + c], 1);
  }
}

__global__ void k_offsets(const int* __restrict__ counts, int2* __restrict__ oc,
                          int* __restrict__ cursor, int* __restrict__ gcount) {
  __shared__ int lds[256];
  __shared__ int basesh;
  int tid = threadIdx.x;
  int i = blockIdx.x * 256 + tid;
  int c = (i < CC * NN) ? counts[i] : 0;
  lds[tid] = c;
  __syncthreads();
  int v = c;
  for (int s = 1; s < 256; s <<= 1) {
    int t = (tid >= s) ? lds[tid - s] : 0;
    __syncthreads();
    v += t;
    lds[tid] = v;
    __syncthreads();
  }
  if (tid == 255) basesh = atomicAdd(gcount, v);
  __syncthreads();
  int excl = basesh + v - c;
  if (i < CC * NN) {
    oc[i] = make_int2(excl, c);
    cursor[i] = excl;
  }
}

// slot value packs src and colour: sv = src*8 + c
__global__ void k_fill(const int* __restrict__ ei, const int* __restrict__ ec,
                       int* __restrict__ cursor, int* __restrict__ sv) {
  int e = blockIdx.x * 256 + threadIdx.x;
  if (e < EE) {
    int src = ei[e];
    int dst = ei[EE + e];
    int c = ec[e];
    int slot = atomicAdd(&cursor[dst * CC + c], 1);
    sv[slot] = src * 8 + c;
  }
}

// ---------------- layer 1: balanced pure gather ----------------
// thread = (dst, 16B-chunk): 800k threads, grid 3125.

__global__ void __launch_bounds__(256) k_agg1(
    const u16* __restrict__ xb, const int2* __restrict__ oc,
    const int* __restrict__ sv, u16* __restrict__ agg) {
  int item = blockIdx.x * 256 + threadIdx.x;
  int dst = item >> 4, ch = item & 15;
  int eoff = ch * 8;
#pragma unroll
  for (int c = 0; c < CC; ++c) {
    int2 se = oc[dst * CC + c];
    float s[8];
#pragma unroll
    for (int q = 0; q < 8; q++) s[q] = 0.f;
    int j = 0;
    for (; j + 1 < se.y; j += 2) {
      int s0 = sv[se.x + j] >> 3;
      int s1 = sv[se.x + j + 1] >> 3;
      s16x8 v0 = *(const s16x8*)(xb + (size_t)s0 * DD + eoff);
      s16x8 v1 = *(const s16x8*)(xb + (size_t)s1 * DD + eoff);
#pragma unroll
      for (int q = 0; q < 8; q++) s[q] += bf2f(v0[q]) + bf2f(v1[q]);
    }
    if (j < se.y) {
      int s0 = sv[se.x + j] >> 3;
      s16x8 v0 = *(const s16x8*)(xb + (size_t)s0 * DD + eoff);
#pragma unroll
      for (int q = 0; q < 8; q++) s[q] += bf2f(v0[q]);
    }
    s16x8 r;
#pragma unroll
    for (int q = 0; q < 8; q++) r[q] = (short)f2bf(s[q]);
    *(s16x8*)(agg + ((size_t)c * NN + dst) * DD + eoff) = r;
  }
}

// ---------------- layer 1 dense: 64-row waves ----------------
// Wave: 64 rows x 128 cols, acc[4][8]. Block 4 waves (2rt x 2ch) = 128 x 256.

__global__ void __launch_bounds__(256, 2) k_gemm1s(
    const u16* __restrict__ xb, const u16* __restrict__ agg,
    const u16* __restrict__ Wf, const float* __restrict__ b1,
    u16* __restrict__ hb) {
  int tid = threadIdx.x;
  int w = tid >> 6, lane = tid & 63;
  int rs = lane & 15, kg = lane >> 4;
  int rt = w >> 1, ch = w & 1;
  int r0 = blockIdx.x * 128 + rt * 64;

  int rowA[4];
#pragma unroll
  for (int rg = 0; rg < 4; ++rg) rowA[rg] = min(r0 + rg * 16 + rs, NN - 1);

  f32x4 acc[4][8];
#pragma unroll
  for (int rg = 0; rg < 4; ++rg)
#pragma unroll
    for (int i = 0; i < 8; i++)
#pragma unroll
      for (int q = 0; q < 4; q++) acc[rg][i][q] = 0.f;

  for (int c = 0; c < CC; ++c) {
#pragma unroll
    for (int kk = 0; kk < 4; ++kk) {
      int kkg = c * 4 + kk;
      s16x8 af[4];
#pragma unroll
      for (int rg = 0; rg < 4; ++rg)
        af[rg] = *(const s16x8*)(agg + ((size_t)c * NN + rowA[rg]) * DD + kk * 32 + kg * 8);
#pragma unroll
      for (int fc = 0; fc < 8; ++fc) {
        int col16 = ch * 8 + fc;
        s16x8 bfr = *(const s16x8*)(Wf + (size_t)(col16 * 36 + kkg) * 512 + lane * 8);
#pragma unroll
        for (int rg = 0; rg < 4; ++rg)
          acc[rg][fc] = __builtin_amdgcn_mfma_f32_16x16x32_bf16(af[rg], bfr, acc[rg][fc], 0, 0, 0);
      }
    }
  }
#pragma unroll
  for (int kk = 0; kk < 4; ++kk) {           // self block (k 1024..1151)
    int kkg = 32 + kk;
    s16x8 af[4];
#pragma unroll
    for (int rg = 0; rg < 4; ++rg)
      af[rg] = *(const s16x8*)(xb + (size_t)rowA[rg] * DD + kk * 32 + kg * 8);
#pragma unroll
    for (int fc = 0; fc < 8; ++fc) {
      int col16 = ch * 8 + fc;
      s16x8 bfr = *(const s16x8*)(Wf + (size_t)(col16 * 36 + kkg) * 512 + lane * 8);
#pragma unroll
      for (int rg = 0; rg < 4; ++rg)
        acc[rg][fc] = __builtin_amdgcn_mfma_f32_16x16x32_bf16(af[rg], bfr, acc[rg][fc], 0, 0, 0);
    }
  }

#pragma unroll
  for (int fc = 0; fc < 8; ++fc) {
    int col = ch * 128 + fc * 16 + rs;
    float bias = b1[col];
#pragma unroll
    for (int rg = 0; rg < 4; ++rg) {
#pragma unroll
      for (int q = 0; q < 4; ++q) {
        float v = acc[rg][fc][q] + bias;
        if (v < 0.f) v = 0.f;
        int rr = r0 + rg * 16 + kg * 4 + q;
        if (rr < NN) hb[(size_t)rr * HH + col] = f2bf(v);
      }
    }
  }
}

// ---------------- layer 2 multiply-first: 32-row waves, 4 waves/SIMD ----------
// Wave: 32 rows x 96 cols, acc[2][6]. Block 4 ch-waves = 32 x 384.
// Grid (3 colblocks, 1563 rowblocks).

__global__ void __launch_bounds__(256, 4) k_gemm2g(
    const u16* __restrict__ hb, const u16* __restrict__ Wf,
    u16* __restrict__ g2) {
  int cb = blockIdx.x;          // 0..2
  int rb = blockIdx.y;          // 0..1562
  int tid = threadIdx.x;
  int ch = tid >> 6, lane = tid & 63;
  int rs = lane & 15, kg = lane >> 4;
  int r0 = rb * 32;
  int c16b = cb * 24 + ch * 6;

  int rowA[2];
#pragma unroll
  for (int rg = 0; rg < 2; ++rg) rowA[rg] = min(r0 + rg * 16 + rs, NN - 1);

  f32x4 acc[2][6];
#pragma unroll
  for (int rg = 0; rg < 2; ++rg)
#pragma unroll
    for (int i = 0; i < 6; i++)
#pragma unroll
      for (int q = 0; q < 4; q++) acc[rg][i][q] = 0.f;

#pragma unroll
  for (int kk = 0; kk < 8; ++kk) {
    s16x8 af[2];
#pragma unroll
    for (int rg = 0; rg < 2; ++rg)
      af[rg] = *(const s16x8*)(hb + (size_t)rowA[rg] * HH + kk * 32 + kg * 8);
#pragma unroll
    for (int fc = 0; fc < 6; ++fc) {
      s16x8 bfr = *(const s16x8*)(Wf + (size_t)((c16b + fc) * 8 + kk) * 512 + lane * 8);
#pragma unroll
      for (int rg = 0; rg < 2; ++rg)
        acc[rg][fc] = __builtin_amdgcn_mfma_f32_16x16x32_bf16(af[rg], bfr, acc[rg][fc], 0, 0, 0);
    }
  }
#pragma unroll
  for (int rg = 0; rg < 2; ++rg) {
#pragma unroll
    for (int q = 0; q < 4; ++q) {
      int rr = r0 + rg * 16 + kg * 4 + q;
      if (rr < NN) {
#pragma unroll
        for (int fc = 0; fc < 6; ++fc) {
          int col = (c16b + fc) * 16 + rs;
          g2[(size_t)rr * 1152 + col] = f2bf(acc[rg][fc][q]);
        }
      }
    }
  }
}

// ---------------- layer 2 final: flattened gather-sum-sigmoid ----------------
// thread = (dst, 32B-chunk): 400k threads. One contiguous ~16-edge walk per
// dst (colour segments are adjacent); 4-edge batched prefetch; per-edge g2
// offset decoded from sv.

__global__ void __launch_bounds__(256) k_final(
    const u16* __restrict__ g2, const float* __restrict__ b2,
    const int2* __restrict__ oc, const int* __restrict__ sv,
    float* __restrict__ out) {
  int item = blockIdx.x * 256 + threadIdx.x;
  if (item >= NN * 8) return;
  int dst = item >> 3, ch = item & 7;
  int eoff = ch * 16;

  int st, cn;
  {
    int2 a0 = oc[dst * CC];
    int2 a7 = oc[dst * CC + 7];
    st = a0.x;
    cn = a7.x + a7.y - a0.x;
  }

  float s[16];
  {
    const u16* sp = g2 + (size_t)dst * 1152 + 1024 + eoff;
    s16x8 lo = *(const s16x8*)sp;
    s16x8 hi = *(const s16x8*)(sp + 8);
#pragma unroll
    for (int q = 0; q < 8; q++) s[q] = b2[eoff + q] + bf2f(lo[q]);
#pragma unroll
    for (int q = 0; q < 8; q++) s[q + 8] = b2[eoff + 8 + q] + bf2f(hi[q]);
  }

  for (int j = 0; j < cn; j += 4) {
    int pofs[4];
#pragma unroll
    for (int t = 0; t < 4; t++) {
      int jj = j + t;
      if (jj < cn) {
        int v = sv[st + jj];
        pofs[t] = (v >> 3) * 1152 + (v & 7) * 128;
      } else {
        pofs[t] = -1;
      }
    }
#pragma unroll
    for (int t = 0; t < 4; t++) {
      if (pofs[t] >= 0) {
        const u16* pp = g2 + pofs[t] + eoff;
        s16x8 lo = *(const s16x8*)pp;
        s16x8 hi = *(const s16x8*)(pp + 8);
#pragma unroll
        for (int q = 0; q < 8; q++) s[q] += bf2f(lo[q]);
#pragma unroll
        for (int q = 0; q < 8; q++) s[q + 8] += bf2f(hi[q]);
      }
    }
  }
  float* op = out + (size_t)dst * DD + eoff;
#pragma unroll
  for (int q = 0; q < 16; q++) op[q] = 1.f / (1.f + expf(10.f - s[q]));
}

// ---------------- launch ----------------

extern "C" void kernel_launch(void* const* d_in, const int* in_sizes, int n_in,
                              void* d_out, int out_size, void* d_ws, size_t ws_size,
                              hipStream_t stream) {
  const float* x   = (const float*)d_in[0];
  const int*   ei  = (const int*)d_in[1];
  const int*   ec  = (const int*)d_in[2];
  const float* Ws1 = (const float*)d_in[3];
  const float* b1  = (const float*)d_in[4];
  const float* Ws2 = (const float*)d_in[5];
  const float* b2  = (const float*)d_in[6];
  const float* Wc1 = (const float*)d_in[7];
  const float* Wc2 = (const float*)d_in[8];
  float* out = (float*)d_out;

  char* p = (char*)d_ws;
  // g2 [N,1152] bf16 (115.2MB) aliases agg1 (102.4MB) + xb (12.8MB).
  u16*  g2     = (u16*)p;
  u16*  agg1   = (u16*)p;                         // [C*N,128] bf16
  u16*  xb     = (u16*)(p + 102400000);           // [N,128] bf16
  u16*  hb     = (u16*)(p + 115200000);           // [N,256] bf16
  u16*  W1f    = (u16*)(p + 140800000);           // frag-major
  u16*  W2f    = (u16*)(p + 141389824);           // frag-major
  int2* oc     = (int2*)(p + 141979648);          // [N*C] {off,cnt}
  int*  sv     = (int*)(p + 145179648);           // [E] src*8+c
  int*  counts = (int*)(p + 148379648);           // [N*C]
  int*  gcount = (int*)(p + 149979648);
  int*  cursor = (int*)(p + 149979904);           // [N*C]

  hipMemsetAsync(counts, 0, 1600256, stream);     // counts + gcount

  k_castx<<<25000, 256, 0, stream>>>(x, xb);
  k_wt1f<<<1152, 256, 0, stream>>>(Wc1, Ws1, W1f);
  k_wt2f<<<1152, 256, 0, stream>>>(Wc2, Ws2, W2f);

  k_hist<<<3125, 256, 0, stream>>>(ei, ec, counts);
  k_offsets<<<1563, 256, 0, stream>>>(counts, oc, cursor, gcount);
  k_fill<<<3125, 256, 0, stream>>>(ei, ec, cursor, sv);

  k_agg1<<<3125, 256, 0, stream>>>(xb, oc, sv, agg1);
  k_gemm1s<<<391, 256, 0, stream>>>(xb, agg1, W1f, b1, hb);
  k_gemm2g<<<dim3(3, 1563), 256, 0, stream>>>(hb, W2f, g2);
  k_final<<<1563, 256, 0, stream>>>(g2, b2, oc, sv, out);
}

// Round 16
// 350.488 us; speedup vs baseline: 1.0622x; 1.0622x over previous
//
#include <hip/hip_runtime.h>

// GNN: 2-layer edge-coloured conv on MI355X.
// Round 16: k_gemm2g weight-stationary: block stages its 96-col B panel
// (48KB, contiguous in frag-major W2f) into LDS once, 4 waves sweep 256 rows
// (2x32-row chunks each) with hoisted A-loads; B-latency eliminated, B L2
// traffic /8. Everything else = round 15 (passed, 372us).

#define NN 50000
#define EE 800000
#define DD 128
#define HH 256
#define CC 8
#define K1 1152   // C*D + D

typedef unsigned short u16;
typedef __attribute__((ext_vector_type(8))) short s16x8;
typedef __attribute__((ext_vector_type(4))) float f32x4;

__device__ __forceinline__ float bf2f(short u) {
  return __uint_as_float(((unsigned)(u16)u) << 16);
}
__device__ __forceinline__ u16 f2bf(float f) {
  unsigned u = __float_as_uint(f);
  u = (u + 0x7FFFu + ((u >> 16) & 1u)) >> 16;   // RNE
  return (u16)u;
}

// ---------------- prep ----------------

__global__ void k_castx(const float* __restrict__ x, u16* __restrict__ xb) {
  int i = blockIdx.x * 256 + threadIdx.x;
  if (i < NN * DD) xb[i] = f2bf(x[i]);
}

// W1f fragment-major: idx = (((col16*36 + kk)*4 + kg)*16 + rs)*8 + e
__global__ void k_wt1f(const float* __restrict__ Wc1, const float* __restrict__ Ws1,
                       u16* __restrict__ W) {
  int i = blockIdx.x * 256 + threadIdx.x;
  if (i >= 294912) return;
  int e = i & 7;
  int t = i >> 3;
  int rs = t & 15; t >>= 4;
  int kg = t & 3;  t >>= 2;
  int kk = t % 36;
  int col16 = t / 36;
  int col = col16 * 16 + rs;
  int k = kk * 32 + kg * 8 + e;
  float v = (k < CC * DD) ? Wc1[(k >> 7) * (HH * DD) + col * DD + (k & 127)]
                          : Ws1[col * DD + (k - CC * DD)];
  W[i] = f2bf(v);
}

// W2f fragment-major: idx = (((col16*8 + kk)*4 + kg)*16 + rs)*8 + e
__global__ void k_wt2f(const float* __restrict__ Wc2, const float* __restrict__ Ws2,
                       u16* __restrict__ W) {
  int i = blockIdx.x * 256 + threadIdx.x;
  if (i >= 294912) return;
  int e = i & 7;
  int t = i >> 3;
  int rs = t & 15; t >>= 4;
  int kg = t & 3;  t >>= 2;
  int kk = t & 7;
  int col16 = t >> 3;
  int oc = col16 * 16 + rs;
  int c = oc >> 7, o = oc & 127;
  int k = kk * 32 + kg * 8 + e;
  float v = (c < CC) ? Wc2[c * (DD * HH) + o * HH + k] : Ws2[o * HH + k];
  W[i] = f2bf(v);
}

// ---------------- CSR build over seg = dst*8 + c ----------------

__global__ void k_hist(const int* __restrict__ ei, const int* __restrict__ ec,
                       int* __restrict__ counts) {
  int e = blockIdx.x * 256 + threadIdx.x;
  if (e < EE) {
    int dst = ei[EE + e];
    int c = ec[e];
    atomicAdd(&counts[dst * CC + c], 1);
  }
}

__global__ void k_offsets(const int* __restrict__ counts, int2* __restrict__ oc,
                          int* __restrict__ cursor, int* __restrict__ gcount) {
  __shared__ int lds[256];
  __shared__ int basesh;
  int tid = threadIdx.x;
  int i = blockIdx.x * 256 + tid;
  int c = (i < CC * NN) ? counts[i] : 0;
  lds[tid] = c;
  __syncthreads();
  int v = c;
  for (int s = 1; s < 256; s <<= 1) {
    int t = (tid >= s) ? lds[tid - s] : 0;
    __syncthreads();
    v += t;
    lds[tid] = v;
    __syncthreads();
  }
  if (tid == 255) basesh = atomicAdd(gcount, v);
  __syncthreads();
  int excl = basesh + v - c;
  if (i < CC * NN) {
    oc[i] = make_int2(excl, c);
    cursor[i] = excl;
  }
}

// slot value packs src and colour: sv = src*8 + c
__global__ void k_fill(const int* __restrict__ ei, const int* __restrict__ ec,
                       int* __restrict__ cursor, int* __restrict__ sv) {
  int e = blockIdx.x * 256 + threadIdx.x;
  if (e < EE) {
    int src = ei[e];
    int dst = ei[EE + e];
    int c = ec[e];
    int slot = atomicAdd(&cursor[dst * CC + c], 1);
    sv[slot] = src * 8 + c;
  }
}

// ---------------- layer 1: balanced pure gather ----------------

__global__ void __launch_bounds__(256) k_agg1(
    const u16* __restrict__ xb, const int2* __restrict__ oc,
    const int* __restrict__ sv, u16* __restrict__ agg) {
  int item = blockIdx.x * 256 + threadIdx.x;
  int dst = item >> 4, ch = item & 15;
  int eoff = ch * 8;
#pragma unroll
  for (int c = 0; c < CC; ++c) {
    int2 se = oc[dst * CC + c];
    float s[8];
#pragma unroll
    for (int q = 0; q < 8; q++) s[q] = 0.f;
    int j = 0;
    for (; j + 1 < se.y; j += 2) {
      int s0 = sv[se.x + j] >> 3;
      int s1 = sv[se.x + j + 1] >> 3;
      s16x8 v0 = *(const s16x8*)(xb + (size_t)s0 * DD + eoff);
      s16x8 v1 = *(const s16x8*)(xb + (size_t)s1 * DD + eoff);
#pragma unroll
      for (int q = 0; q < 8; q++) s[q] += bf2f(v0[q]) + bf2f(v1[q]);
    }
    if (j < se.y) {
      int s0 = sv[se.x + j] >> 3;
      s16x8 v0 = *(const s16x8*)(xb + (size_t)s0 * DD + eoff);
#pragma unroll
      for (int q = 0; q < 8; q++) s[q] += bf2f(v0[q]);
    }
    s16x8 r;
#pragma unroll
    for (int q = 0; q < 8; q++) r[q] = (short)f2bf(s[q]);
    *(s16x8*)(agg + ((size_t)c * NN + dst) * DD + eoff) = r;
  }
}

// ---------------- layer 1 dense: 64-row waves ----------------

__global__ void __launch_bounds__(256, 2) k_gemm1s(
    const u16* __restrict__ xb, const u16* __restrict__ agg,
    const u16* __restrict__ Wf, const float* __restrict__ b1,
    u16* __restrict__ hb) {
  int tid = threadIdx.x;
  int w = tid >> 6, lane = tid & 63;
  int rs = lane & 15, kg = lane >> 4;
  int rt = w >> 1, ch = w & 1;
  int r0 = blockIdx.x * 128 + rt * 64;

  int rowA[4];
#pragma unroll
  for (int rg = 0; rg < 4; ++rg) rowA[rg] = min(r0 + rg * 16 + rs, NN - 1);

  f32x4 acc[4][8];
#pragma unroll
  for (int rg = 0; rg < 4; ++rg)
#pragma unroll
    for (int i = 0; i < 8; i++)
#pragma unroll
      for (int q = 0; q < 4; q++) acc[rg][i][q] = 0.f;

  for (int c = 0; c < CC; ++c) {
#pragma unroll
    for (int kk = 0; kk < 4; ++kk) {
      int kkg = c * 4 + kk;
      s16x8 af[4];
#pragma unroll
      for (int rg = 0; rg < 4; ++rg)
        af[rg] = *(const s16x8*)(agg + ((size_t)c * NN + rowA[rg]) * DD + kk * 32 + kg * 8);
#pragma unroll
      for (int fc = 0; fc < 8; ++fc) {
        int col16 = ch * 8 + fc;
        s16x8 bfr = *(const s16x8*)(Wf + (size_t)(col16 * 36 + kkg) * 512 + lane * 8);
#pragma unroll
        for (int rg = 0; rg < 4; ++rg)
          acc[rg][fc] = __builtin_amdgcn_mfma_f32_16x16x32_bf16(af[rg], bfr, acc[rg][fc], 0, 0, 0);
      }
    }
  }
#pragma unroll
  for (int kk = 0; kk < 4; ++kk) {           // self block (k 1024..1151)
    int kkg = 32 + kk;
    s16x8 af[4];
#pragma unroll
    for (int rg = 0; rg < 4; ++rg)
      af[rg] = *(const s16x8*)(xb + (size_t)rowA[rg] * DD + kk * 32 + kg * 8);
#pragma unroll
    for (int fc = 0; fc < 8; ++fc) {
      int col16 = ch * 8 + fc;
      s16x8 bfr = *(const s16x8*)(Wf + (size_t)(col16 * 36 + kkg) * 512 + lane * 8);
#pragma unroll
      for (int rg = 0; rg < 4; ++rg)
        acc[rg][fc] = __builtin_amdgcn_mfma_f32_16x16x32_bf16(af[rg], bfr, acc[rg][fc], 0, 0, 0);
    }
  }

#pragma unroll
  for (int fc = 0; fc < 8; ++fc) {
    int col = ch * 128 + fc * 16 + rs;
    float bias = b1[col];
#pragma unroll
    for (int rg = 0; rg < 4; ++rg) {
#pragma unroll
      for (int q = 0; q < 4; ++q) {
        float v = acc[rg][fc][q] + bias;
        if (v < 0.f) v = 0.f;
        int rr = r0 + rg * 16 + kg * 4 + q;
        if (rr < NN) hb[(size_t)rr * HH + col] = f2bf(v);
      }
    }
  }
}

// ---------------- layer 2 multiply-first: weight-stationary LDS-B ----------
// Grid (12 col-panels, 196 row-blocks). Block: stage 96-col x K=256 B panel
// (48KB, contiguous W2f slice) into LDS once; 4 waves sweep 256 rows
// (2 chunks x 32 rows each). Per chunk: 16 hoisted A-loads, 48 ds_read_b128
// (consecutive-lane, conflict-free), 96 MFMA.

__global__ void __launch_bounds__(256, 3) k_gemm2g(
    const u16* __restrict__ hb, const u16* __restrict__ Wf,
    u16* __restrict__ g2) {
  __shared__ u16 Bs[24576];               // 48KB
  int cb = blockIdx.x;                    // 0..11
  int rb = blockIdx.y;                    // 0..195
  int tid = threadIdx.x;
  int w = tid >> 6, lane = tid & 63;
  int rs = lane & 15, kg = lane >> 4;
  int c16b = cb * 6;

  // stage B panel: W2f slice [cb*24576 .. +24576) u16, linear copy
  {
    const u16* src = Wf + (size_t)cb * 24576;
#pragma unroll
    for (int i = 0; i < 12; ++i) {
      int o = (i * 256 + tid) * 8;
      *(s16x8*)(Bs + o) = *(const s16x8*)(src + o);
    }
  }
  __syncthreads();

#pragma unroll
  for (int tt = 0; tt < 2; ++tt) {
    int t = w + tt * 4;                   // chunk index 0..7
    int r0 = rb * 256 + t * 32;
    int rowA[2];
#pragma unroll
    for (int rg = 0; rg < 2; ++rg) rowA[rg] = min(r0 + rg * 16 + rs, NN - 1);

    // hoist all A loads for this chunk
    s16x8 af[2][8];
#pragma unroll
    for (int rg = 0; rg < 2; ++rg)
#pragma unroll
      for (int kk = 0; kk < 8; ++kk)
        af[rg][kk] = *(const s16x8*)(hb + (size_t)rowA[rg] * HH + kk * 32 + kg * 8);

    f32x4 acc[2][6];
#pragma unroll
    for (int rg = 0; rg < 2; ++rg)
#pragma unroll
      for (int i = 0; i < 6; i++)
#pragma unroll
        for (int q = 0; q < 4; q++) acc[rg][i][q] = 0.f;

#pragma unroll
    for (int kk = 0; kk < 8; ++kk) {
#pragma unroll
      for (int fc = 0; fc < 6; ++fc) {
        s16x8 bfr = *(const s16x8*)(Bs + ((fc * 8 + kk) * 64 + lane) * 8);
#pragma unroll
        for (int rg = 0; rg < 2; ++rg)
          acc[rg][fc] = __builtin_amdgcn_mfma_f32_16x16x32_bf16(af[rg][kk], bfr, acc[rg][fc], 0, 0, 0);
      }
    }

#pragma unroll
    for (int rg = 0; rg < 2; ++rg) {
#pragma unroll
      for (int q = 0; q < 4; ++q) {
        int rr = r0 + rg * 16 + kg * 4 + q;
        if (rr < NN) {
#pragma unroll
          for (int fc = 0; fc < 6; ++fc) {
            int col = (c16b + fc) * 16 + rs;
            g2[(size_t)rr * 1152 + col] = f2bf(acc[rg][fc][q]);
          }
        }
      }
    }
  }
}

// ---------------- layer 2 final: flattened gather-sum-sigmoid ----------------

__global__ void __launch_bounds__(256) k_final(
    const u16* __restrict__ g2, const float* __restrict__ b2,
    const int2* __restrict__ oc, const int* __restrict__ sv,
    float* __restrict__ out) {
  int item = blockIdx.x * 256 + threadIdx.x;
  if (item >= NN * 8) return;
  int dst = item >> 3, ch = item & 7;
  int eoff = ch * 16;

  int st, cn;
  {
    int2 a0 = oc[dst * CC];
    int2 a7 = oc[dst * CC + 7];
    st = a0.x;
    cn = a7.x + a7.y - a0.x;
  }

  float s[16];
  {
    const u16* sp = g2 + (size_t)dst * 1152 + 1024 + eoff;
    s16x8 lo = *(const s16x8*)sp;
    s16x8 hi = *(const s16x8*)(sp + 8);
#pragma unroll
    for (int q = 0; q < 8; q++) s[q] = b2[eoff + q] + bf2f(lo[q]);
#pragma unroll
    for (int q = 0; q < 8; q++) s[q + 8] = b2[eoff + 8 + q] + bf2f(hi[q]);
  }

  for (int j = 0; j < cn; j += 4) {
    int pofs[4];
#pragma unroll
    for (int t = 0; t < 4; t++) {
      int jj = j + t;
      if (jj < cn) {
        int v = sv[st + jj];
        pofs[t] = (v >> 3) * 1152 + (v & 7) * 128;
      } else {
        pofs[t] = -1;
      }
    }
#pragma unroll
    for (int t = 0; t < 4; t++) {
      if (pofs[t] >= 0) {
        const u16* pp = g2 + pofs[t] + eoff;
        s16x8 lo = *(const s16x8*)pp;
        s16x8 hi = *(const s16x8*)(pp + 8);
#pragma unroll
        for (int q = 0; q < 8; q++) s[q] += bf2f(lo[q]);
#pragma unroll
        for (int q = 0; q < 8; q++) s[q + 8] += bf2f(hi[q]);
      }
    }
  }
  float* op = out + (size_t)dst * DD + eoff;
#pragma unroll
  for (int q = 0; q < 16; q++) op[q] = 1.f / (1.f + expf(10.f - s[q]));
}

// ---------------- launch ----------------

extern "C" void kernel_launch(void* const* d_in, const int* in_sizes, int n_in,
                              void* d_out, int out_size, void* d_ws, size_t ws_size,
                              hipStream_t stream) {
  const float* x   = (const float*)d_in[0];
  const int*   ei  = (const int*)d_in[1];
  const int*   ec  = (const int*)d_in[2];
  const float* Ws1 = (const float*)d_in[3];
  const float* b1  = (const float*)d_in[4];
  const float* Ws2 = (const float*)d_in[5];
  const float* b2  = (const float*)d_in[6];
  const float* Wc1 = (const float*)d_in[7];
  const float* Wc2 = (const float*)d_in[8];
  float* out = (float*)d_out;

  char* p = (char*)d_ws;
  // g2 [N,1152] bf16 (115.2MB) aliases agg1 (102.4MB) + xb (12.8MB).
  u16*  g2     = (u16*)p;
  u16*  agg1   = (u16*)p;                         // [C*N,128] bf16
  u16*  xb     = (u16*)(p + 102400000);           // [N,128] bf16
  u16*  hb     = (u16*)(p + 115200000);           // [N,256] bf16
  u16*  W1f    = (u16*)(p + 140800000);           // frag-major
  u16*  W2f    = (u16*)(p + 141389824);           // frag-major
  int2* oc     = (int2*)(p + 141979648);          // [N*C] {off,cnt}
  int*  sv     = (int*)(p + 145179648);           // [E] src*8+c
  int*  counts = (int*)(p + 148379648);           // [N*C]
  int*  gcount = (int*)(p + 149979648);
  int*  cursor = (int*)(p + 149979904);           // [N*C]

  hipMemsetAsync(counts, 0, 1600256, stream);     // counts + gcount

  k_castx<<<25000, 256, 0, stream>>>(x, xb);
  k_wt1f<<<1152, 256, 0, stream>>>(Wc1, Ws1, W1f);
  k_wt2f<<<1152, 256, 0, stream>>>(Wc2, Ws2, W2f);

  k_hist<<<3125, 256, 0, stream>>>(ei, ec, counts);
  k_offsets<<<1563, 256, 0, stream>>>(counts, oc, cursor, gcount);
  k_fill<<<3125, 256, 0, stream>>>(ei, ec, cursor, sv);

  k_agg1<<<3125, 256, 0, stream>>>(xb, oc, sv, agg1);
  k_gemm1s<<<391, 256, 0, stream>>>(xb, agg1, W1f, b1, hb);
  k_gemm2g<<<dim3(12, 196), 256, 0, stream>>>(hb, W2f, g2);
  k_final<<<1563, 256, 0, stream>>>(g2, b2, oc, sv, out);
}

// Round 17
// 340.998 us; speedup vs baseline: 1.0918x; 1.0278x over previous
//
#include <hip/hip_runtime.h>

// GNN: 2-layer edge-coloured conv on MI355X.
// Round 17: k_gemm1s gets the gemm2g treatment — per-colour 32KB LDS-staged
// B panels, 32-row waves (acc[2][8]), grid (2 ch x 391 rb) = 782 blocks,
// 4 waves/SIMD. 9 phases x (stage, barrier, 64 MFMA/wave, barrier).
// Everything else = round 16 (passed, 350us).

#define NN 50000
#define EE 800000
#define DD 128
#define HH 256
#define CC 8
#define K1 1152   // C*D + D

typedef unsigned short u16;
typedef __attribute__((ext_vector_type(8))) short s16x8;
typedef __attribute__((ext_vector_type(4))) float f32x4;

__device__ __forceinline__ float bf2f(short u) {
  return __uint_as_float(((unsigned)(u16)u) << 16);
}
__device__ __forceinline__ u16 f2bf(float f) {
  unsigned u = __float_as_uint(f);
  u = (u + 0x7FFFu + ((u >> 16) & 1u)) >> 16;   // RNE
  return (u16)u;
}

// ---------------- prep ----------------

__global__ void k_castx(const float* __restrict__ x, u16* __restrict__ xb) {
  int i = blockIdx.x * 256 + threadIdx.x;
  if (i < NN * DD) xb[i] = f2bf(x[i]);
}

// W1f fragment-major: idx = (((col16*36 + kk)*4 + kg)*16 + rs)*8 + e
__global__ void k_wt1f(const float* __restrict__ Wc1, const float* __restrict__ Ws1,
                       u16* __restrict__ W) {
  int i = blockIdx.x * 256 + threadIdx.x;
  if (i >= 294912) return;
  int e = i & 7;
  int t = i >> 3;
  int rs = t & 15; t >>= 4;
  int kg = t & 3;  t >>= 2;
  int kk = t % 36;
  int col16 = t / 36;
  int col = col16 * 16 + rs;
  int k = kk * 32 + kg * 8 + e;
  float v = (k < CC * DD) ? Wc1[(k >> 7) * (HH * DD) + col * DD + (k & 127)]
                          : Ws1[col * DD + (k - CC * DD)];
  W[i] = f2bf(v);
}

// W2f fragment-major: idx = (((col16*8 + kk)*4 + kg)*16 + rs)*8 + e
__global__ void k_wt2f(const float* __restrict__ Wc2, const float* __restrict__ Ws2,
                       u16* __restrict__ W) {
  int i = blockIdx.x * 256 + threadIdx.x;
  if (i >= 294912) return;
  int e = i & 7;
  int t = i >> 3;
  int rs = t & 15; t >>= 4;
  int kg = t & 3;  t >>= 2;
  int kk = t & 7;
  int col16 = t >> 3;
  int oc = col16 * 16 + rs;
  int c = oc >> 7, o = oc & 127;
  int k = kk * 32 + kg * 8 + e;
  float v = (c < CC) ? Wc2[c * (DD * HH) + o * HH + k] : Ws2[o * HH + k];
  W[i] = f2bf(v);
}

// ---------------- CSR build over seg = dst*8 + c ----------------

__global__ void k_hist(const int* __restrict__ ei, const int* __restrict__ ec,
                       int* __restrict__ counts) {
  int e = blockIdx.x * 256 + threadIdx.x;
  if (e < EE) {
    int dst = ei[EE + e];
    int c = ec[e];
    atomicAdd(&counts[dst * CC + c], 1);
  }
}

__global__ void k_offsets(const int* __restrict__ counts, int2* __restrict__ oc,
                          int* __restrict__ cursor, int* __restrict__ gcount) {
  __shared__ int lds[256];
  __shared__ int basesh;
  int tid = threadIdx.x;
  int i = blockIdx.x * 256 + tid;
  int c = (i < CC * NN) ? counts[i] : 0;
  lds[tid] = c;
  __syncthreads();
  int v = c;
  for (int s = 1; s < 256; s <<= 1) {
    int t = (tid >= s) ? lds[tid - s] : 0;
    __syncthreads();
    v += t;
    lds[tid] = v;
    __syncthreads();
  }
  if (tid == 255) basesh = atomicAdd(gcount, v);
  __syncthreads();
  int excl = basesh + v - c;
  if (i < CC * NN) {
    oc[i] = make_int2(excl, c);
    cursor[i] = excl;
  }
}

// slot value packs src and colour: sv = src*8 + c
__global__ void k_fill(const int* __restrict__ ei, const int* __restrict__ ec,
                       int* __restrict__ cursor, int* __restrict__ sv) {
  int e = blockIdx.x * 256 + threadIdx.x;
  if (e < EE) {
    int src = ei[e];
    int dst = ei[EE + e];
    int c = ec[e];
    int slot = atomicAdd(&cursor[dst * CC + c], 1);
    sv[slot] = src * 8 + c;
  }
}

// ---------------- layer 1: balanced pure gather ----------------

__global__ void __launch_bounds__(256) k_agg1(
    const u16* __restrict__ xb, const int2* __restrict__ oc,
    const int* __restrict__ sv, u16* __restrict__ agg) {
  int item = blockIdx.x * 256 + threadIdx.x;
  int dst = item >> 4, ch = item & 15;
  int eoff = ch * 8;
#pragma unroll
  for (int c = 0; c < CC; ++c) {
    int2 se = oc[dst * CC + c];
    float s[8];
#pragma unroll
    for (int q = 0; q < 8; q++) s[q] = 0.f;
    int j = 0;
    for (; j + 1 < se.y; j += 2) {
      int s0 = sv[se.x + j] >> 3;
      int s1 = sv[se.x + j + 1] >> 3;
      s16x8 v0 = *(const s16x8*)(xb + (size_t)s0 * DD + eoff);
      s16x8 v1 = *(const s16x8*)(xb + (size_t)s1 * DD + eoff);
#pragma unroll
      for (int q = 0; q < 8; q++) s[q] += bf2f(v0[q]) + bf2f(v1[q]);
    }
    if (j < se.y) {
      int s0 = sv[se.x + j] >> 3;
      s16x8 v0 = *(const s16x8*)(xb + (size_t)s0 * DD + eoff);
#pragma unroll
      for (int q = 0; q < 8; q++) s[q] += bf2f(v0[q]);
    }
    s16x8 r;
#pragma unroll
    for (int q = 0; q < 8; q++) r[q] = (short)f2bf(s[q]);
    *(s16x8*)(agg + ((size_t)c * NN + dst) * DD + eoff) = r;
  }
}

// ---------------- layer 1 dense: per-colour LDS-staged B ----------------
// Grid (2 ch, 391 rb). Block: 128 rows x 128 cols, 4 waves x 32 rows.
// 9 phases: stage 32KB colour panel -> barrier -> 64 MFMA/wave -> barrier.

__global__ void __launch_bounds__(256, 4) k_gemm1s(
    const u16* __restrict__ xb, const u16* __restrict__ agg,
    const u16* __restrict__ Wf, const float* __restrict__ b1,
    u16* __restrict__ hb) {
  __shared__ u16 Bs[16384];               // 32KB: [fc 8][kk 4][lane 64][8]
  int ch = blockIdx.x;                    // 0..1
  int rb = blockIdx.y;                    // 0..390
  int tid = threadIdx.x;
  int w = tid >> 6, lane = tid & 63;
  int rs = lane & 15, kg = lane >> 4;
  int r0 = rb * 128 + w * 32;

  int rowA[2];
#pragma unroll
  for (int rg = 0; rg < 2; ++rg) rowA[rg] = min(r0 + rg * 16 + rs, NN - 1);

  f32x4 acc[2][8];
#pragma unroll
  for (int rg = 0; rg < 2; ++rg)
#pragma unroll
    for (int i = 0; i < 8; i++)
#pragma unroll
      for (int q = 0; q < 4; q++) acc[rg][i][q] = 0.f;

  for (int ph = 0; ph < 9; ++ph) {        // 8 colours + self
    // stage this phase's 32KB panel: Bs[(fc*4+kk)*512 + j*8] <-
    //   W1f[((ch*8+fc)*36 + ph*4+kk)*512 + j*8]
#pragma unroll
    for (int i = 0; i < 8; ++i) {
      int li = i * 256 + tid;             // 0..2047 units of 8 u16
      int fc = li >> 8;
      int u = li & 255;
      int kkl = u >> 6, j = u & 63;
      *(s16x8*)(Bs + (fc * 4 + kkl) * 512 + j * 8) =
          *(const s16x8*)(Wf + (size_t)((ch * 8 + fc) * 36 + ph * 4 + kkl) * 512 + j * 8);
    }
    __syncthreads();

    // A fragments for this phase
    s16x8 af[2][4];
    if (ph < CC) {
#pragma unroll
      for (int rg = 0; rg < 2; ++rg)
#pragma unroll
        for (int kk = 0; kk < 4; ++kk)
          af[rg][kk] = *(const s16x8*)(agg + ((size_t)ph * NN + rowA[rg]) * DD + kk * 32 + kg * 8);
    } else {
#pragma unroll
      for (int rg = 0; rg < 2; ++rg)
#pragma unroll
        for (int kk = 0; kk < 4; ++kk)
          af[rg][kk] = *(const s16x8*)(xb + (size_t)rowA[rg] * DD + kk * 32 + kg * 8);
    }

#pragma unroll
    for (int kk = 0; kk < 4; ++kk) {
#pragma unroll
      for (int fc = 0; fc < 8; ++fc) {
        s16x8 bfr = *(const s16x8*)(Bs + (fc * 4 + kk) * 512 + lane * 8);
#pragma unroll
        for (int rg = 0; rg < 2; ++rg)
          acc[rg][fc] = __builtin_amdgcn_mfma_f32_16x16x32_bf16(af[rg][kk], bfr, acc[rg][fc], 0, 0, 0);
      }
    }
    __syncthreads();
  }

#pragma unroll
  for (int fc = 0; fc < 8; ++fc) {
    int col = ch * 128 + fc * 16 + rs;
    float bias = b1[col];
#pragma unroll
    for (int rg = 0; rg < 2; ++rg) {
#pragma unroll
      for (int q = 0; q < 4; ++q) {
        float v = acc[rg][fc][q] + bias;
        if (v < 0.f) v = 0.f;
        int rr = r0 + rg * 16 + kg * 4 + q;
        if (rr < NN) hb[(size_t)rr * HH + col] = f2bf(v);
      }
    }
  }
}

// ---------------- layer 2 multiply-first: weight-stationary LDS-B ----------

__global__ void __launch_bounds__(256, 3) k_gemm2g(
    const u16* __restrict__ hb, const u16* __restrict__ Wf,
    u16* __restrict__ g2) {
  __shared__ u16 Bs[24576];               // 48KB
  int cb = blockIdx.x;                    // 0..11
  int rb = blockIdx.y;                    // 0..195
  int tid = threadIdx.x;
  int w = tid >> 6, lane = tid & 63;
  int rs = lane & 15, kg = lane >> 4;
  int c16b = cb * 6;

  {
    const u16* src = Wf + (size_t)cb * 24576;
#pragma unroll
    for (int i = 0; i < 12; ++i) {
      int o = (i * 256 + tid) * 8;
      *(s16x8*)(Bs + o) = *(const s16x8*)(src + o);
    }
  }
  __syncthreads();

#pragma unroll
  for (int tt = 0; tt < 2; ++tt) {
    int t = w + tt * 4;                   // chunk index 0..7
    int r0 = rb * 256 + t * 32;
    int rowA[2];
#pragma unroll
    for (int rg = 0; rg < 2; ++rg) rowA[rg] = min(r0 + rg * 16 + rs, NN - 1);

    s16x8 af[2][8];
#pragma unroll
    for (int rg = 0; rg < 2; ++rg)
#pragma unroll
      for (int kk = 0; kk < 8; ++kk)
        af[rg][kk] = *(const s16x8*)(hb + (size_t)rowA[rg] * HH + kk * 32 + kg * 8);

    f32x4 acc[2][6];
#pragma unroll
    for (int rg = 0; rg < 2; ++rg)
#pragma unroll
      for (int i = 0; i < 6; i++)
#pragma unroll
        for (int q = 0; q < 4; q++) acc[rg][i][q] = 0.f;

#pragma unroll
    for (int kk = 0; kk < 8; ++kk) {
#pragma unroll
      for (int fc = 0; fc < 6; ++fc) {
        s16x8 bfr = *(const s16x8*)(Bs + ((fc * 8 + kk) * 64 + lane) * 8);
#pragma unroll
        for (int rg = 0; rg < 2; ++rg)
          acc[rg][fc] = __builtin_amdgcn_mfma_f32_16x16x32_bf16(af[rg][kk], bfr, acc[rg][fc], 0, 0, 0);
      }
    }

#pragma unroll
    for (int rg = 0; rg < 2; ++rg) {
#pragma unroll
      for (int q = 0; q < 4; ++q) {
        int rr = r0 + rg * 16 + kg * 4 + q;
        if (rr < NN) {
#pragma unroll
          for (int fc = 0; fc < 6; ++fc) {
            int col = (c16b + fc) * 16 + rs;
            g2[(size_t)rr * 1152 + col] = f2bf(acc[rg][fc][q]);
          }
        }
      }
    }
  }
}

// ---------------- layer 2 final: flattened gather-sum-sigmoid ----------------

__global__ void __launch_bounds__(256) k_final(
    const u16* __restrict__ g2, const float* __restrict__ b2,
    const int2* __restrict__ oc, const int* __restrict__ sv,
    float* __restrict__ out) {
  int item = blockIdx.x * 256 + threadIdx.x;
  if (item >= NN * 8) return;
  int dst = item >> 3, ch = item & 7;
  int eoff = ch * 16;

  int st, cn;
  {
    int2 a0 = oc[dst * CC];
    int2 a7 = oc[dst * CC + 7];
    st = a0.x;
    cn = a7.x + a7.y - a0.x;
  }

  float s[16];
  {
    const u16* sp = g2 + (size_t)dst * 1152 + 1024 + eoff;
    s16x8 lo = *(const s16x8*)sp;
    s16x8 hi = *(const s16x8*)(sp + 8);
#pragma unroll
    for (int q = 0; q < 8; q++) s[q] = b2[eoff + q] + bf2f(lo[q]);
#pragma unroll
    for (int q = 0; q < 8; q++) s[q + 8] = b2[eoff + 8 + q] + bf2f(hi[q]);
  }

  for (int j = 0; j < cn; j += 4) {
    int pofs[4];
#pragma unroll
    for (int t = 0; t < 4; t++) {
      int jj = j + t;
      if (jj < cn) {
        int v = sv[st + jj];
        pofs[t] = (v >> 3) * 1152 + (v & 7) * 128;
      } else {
        pofs[t] = -1;
      }
    }
#pragma unroll
    for (int t = 0; t < 4; t++) {
      if (pofs[t] >= 0) {
        const u16* pp = g2 + pofs[t] + eoff;
        s16x8 lo = *(const s16x8*)pp;
        s16x8 hi = *(const s16x8*)(pp + 8);
#pragma unroll
        for (int q = 0; q < 8; q++) s[q] += bf2f(lo[q]);
#pragma unroll
        for (int q = 0; q < 8; q++) s[q + 8] += bf2f(hi[q]);
      }
    }
  }
  float* op = out + (size_t)dst * DD + eoff;
#pragma unroll
  for (int q = 0; q < 16; q++) op[q] = 1.f / (1.f + expf(10.f - s[q]));
}

// ---------------- launch ----------------

extern "C" void kernel_launch(void* const* d_in, const int* in_sizes, int n_in,
                              void* d_out, int out_size, void* d_ws, size_t ws_size,
                              hipStream_t stream) {
  const float* x   = (const float*)d_in[0];
  const int*   ei  = (const int*)d_in[1];
  const int*   ec  = (const int*)d_in[2];
  const float* Ws1 = (const float*)d_in[3];
  const float* b1  = (const float*)d_in[4];
  const float* Ws2 = (const float*)d_in[5];
  const float* b2  = (const float*)d_in[6];
  const float* Wc1 = (const float*)d_in[7];
  const float* Wc2 = (const float*)d_in[8];
  float* out = (float*)d_out;

  char* p = (char*)d_ws;
  // g2 [N,1152] bf16 (115.2MB) aliases agg1 (102.4MB) + xb (12.8MB).
  u16*  g2     = (u16*)p;
  u16*  agg1   = (u16*)p;                         // [C*N,128] bf16
  u16*  xb     = (u16*)(p + 102400000);           // [N,128] bf16
  u16*  hb     = (u16*)(p + 115200000);           // [N,256] bf16
  u16*  W1f    = (u16*)(p + 140800000);           // frag-major
  u16*  W2f    = (u16*)(p + 141389824);           // frag-major
  int2* oc     = (int2*)(p + 141979648);          // [N*C] {off,cnt}
  int*  sv     = (int*)(p + 145179648);           // [E] src*8+c
  int*  counts = (int*)(p + 148379648);           // [N*C]
  int*  gcount = (int*)(p + 149979648);
  int*  cursor = (int*)(p + 149979904);           // [N*C]

  hipMemsetAsync(counts, 0, 1600256, stream);     // counts + gcount

  k_castx<<<25000, 256, 0, stream>>>(x, xb);
  k_wt1f<<<1152, 256, 0, stream>>>(Wc1, Ws1, W1f);
  k_wt2f<<<1152, 256, 0, stream>>>(Wc2, Ws2, W2f);

  k_hist<<<3125, 256, 0, stream>>>(ei, ec, counts);
  k_offsets<<<1563, 256, 0, stream>>>(counts, oc, cursor, gcount);
  k_fill<<<3125, 256, 0, stream>>>(ei, ec, cursor, sv);

  k_agg1<<<3125, 256, 0, stream>>>(xb, oc, sv, agg1);
  k_gemm1s<<<dim3(2, 391), 256, 0, stream>>>(xb, agg1, W1f, b1, hb);
  k_gemm2g<<<dim3(12, 196), 256, 0, stream>>>(hb, W2f, g2);
  k_final<<<1563, 256, 0, stream>>>(g2, b2, oc, sv, out);
}